// Round 1
// baseline (388.932 us; speedup 1.0000x reference)
//
#include <hip/hip_runtime.h>

// Problem constants (match reference)
#define Kk   16
#define Bb   2048
#define Dd   1024
#define dd_  64
#define ROWS 16   // rows per wave in the GEMM kernels

// ---------------------------------------------------------------------------
// xnorm[b] = sum_D x[b,D]^2.  One wave per row.
// ---------------------------------------------------------------------------
__global__ __launch_bounds__(256) void k_xnorm(const float* __restrict__ x,
                                               float* __restrict__ xnorm) {
    int lane = threadIdx.x & 63;
    int w    = threadIdx.x >> 6;
    int b    = blockIdx.x * 4 + w;
    const float* xr = x + (size_t)b * Dd;
    float s = 0.f;
#pragma unroll
    for (int seg = 0; seg < 4; ++seg) {
        float4 v = *reinterpret_cast<const float4*>(xr + seg * 256 + lane * 4);
        s += v.x * v.x + v.y * v.y + v.z * v.z + v.w * v.w;
    }
#pragma unroll
    for (int off = 32; off > 0; off >>= 1) s += __shfl_down(s, off, 64);
    if (lane == 0) xnorm[b] = s;
}

// ---------------------------------------------------------------------------
// Encode: z[k,b,:] = x[b,:] @ Us[k]   (+ znorm[k,b] = ||z||^2)
// Wave = 16 wave-uniform rows (x via s_load) x 64 dd columns (lane).
// Inner step: 1 coalesced vector load of Us + 16 v_fmac with SGPR operand.
// ---------------------------------------------------------------------------
__global__ __launch_bounds__(256) void k_encode(const float* __restrict__ x,
                                                const float* __restrict__ Us,
                                                float* __restrict__ z,
                                                float* __restrict__ znorm) {
    int lane = threadIdx.x & 63;
    int w    = __builtin_amdgcn_readfirstlane(threadIdx.x >> 6);
    int k    = blockIdx.x >> 5;
    int bt   = blockIdx.x & 31;
    int b0   = bt * 64 + w * ROWS;

    const float* __restrict__ Usk = Us + (size_t)k * Dd * dd_;
    const float* __restrict__ xb  = x + (size_t)b0 * Dd;   // wave-uniform base

    float acc[ROWS];
#pragma unroll
    for (int j = 0; j < ROWS; ++j) acc[j] = 0.f;

#pragma unroll 4
    for (int kk = 0; kk < Dd; ++kk) {
        float u = Usk[kk * dd_ + lane];          // coalesced vector load
#pragma unroll
        for (int j = 0; j < ROWS; ++j)
            acc[j] = fmaf(xb[j * Dd + kk], u, acc[j]);  // uniform -> s_load
    }

    float* zr = z + ((size_t)k * Bb + b0) * dd_;
#pragma unroll
    for (int j = 0; j < ROWS; ++j) zr[j * dd_ + lane] = acc[j];

#pragma unroll
    for (int j = 0; j < ROWS; ++j) {
        float s = acc[j] * acc[j];
#pragma unroll
        for (int off = 32; off > 0; off >>= 1) s += __shfl_down(s, off, 64);
        if (lane == 0) znorm[k * Bb + b0 + j] = s;
    }
}

// ---------------------------------------------------------------------------
// Decode: x_[k,b,:] = z[k,b,:] @ Us[k]^T  (+ hatnorm[k,b] = ||x_||^2)
// Us chunk (64 D-rows x 64 dd) transposed through LDS (pad 65 -> 2-way only).
// z rows are wave-uniform -> s_load.
// ---------------------------------------------------------------------------
__global__ __launch_bounds__(256) void k_decode(const float* __restrict__ Us,
                                                const float* __restrict__ z,
                                                float* __restrict__ xhat,
                                                float* __restrict__ hatnorm) {
    __shared__ float uT[64][65];
    int tid  = threadIdx.x;
    int lane = tid & 63;
    int w    = __builtin_amdgcn_readfirstlane(tid >> 6);
    int k    = blockIdx.x >> 5;
    int bt   = blockIdx.x & 31;
    int b0   = bt * 64 + w * ROWS;

    const float* __restrict__ Usk = Us + (size_t)k * Dd * dd_;
    const float* __restrict__ zb  = z + ((size_t)k * Bb + b0) * dd_;  // uniform
    float* __restrict__ xr        = xhat + ((size_t)k * Bb + b0) * Dd;

    float hat[ROWS];
#pragma unroll
    for (int j = 0; j < ROWS; ++j) hat[j] = 0.f;

    for (int Dc = 0; Dc < Dd; Dc += 64) {
        __syncthreads();
        // stage transposed chunk: uT[dd][Dl] = Us[k][Dc+Dl][dd]
#pragma unroll
        for (int i = 0; i < 4; ++i) {
            int f4 = i * 256 + tid;          // 1024 float4 total
            int Dl = f4 >> 4;                // 16 float4 per D-row
            int d0 = (f4 & 15) * 4;
            float4 v = *reinterpret_cast<const float4*>(
                Usk + (size_t)(Dc + Dl) * dd_ + d0);
            uT[d0 + 0][Dl] = v.x;
            uT[d0 + 1][Dl] = v.y;
            uT[d0 + 2][Dl] = v.z;
            uT[d0 + 3][Dl] = v.w;
        }
        __syncthreads();

        float acc[ROWS];
#pragma unroll
        for (int j = 0; j < ROWS; ++j) acc[j] = 0.f;

#pragma unroll 4
        for (int kk = 0; kk < dd_; ++kk) {
            float u = uT[kk][lane];          // conflict-free (2-way) LDS read
#pragma unroll
            for (int j = 0; j < ROWS; ++j)
                acc[j] = fmaf(zb[j * dd_ + kk], u, acc[j]);  // s_load operand
        }

#pragma unroll
        for (int j = 0; j < ROWS; ++j) {
            xr[(size_t)j * Dd + Dc + lane] = acc[j];   // coalesced store
            hat[j] = fmaf(acc[j], acc[j], hat[j]);
        }
    }

#pragma unroll
    for (int j = 0; j < ROWS; ++j) {
        float s = hat[j];
#pragma unroll
        for (int off = 32; off > 0; off >>= 1) s += __shfl_down(s, off, 64);
        if (lane == 0) hatnorm[k * Bb + b0 + j] = s;
    }
}

// ---------------------------------------------------------------------------
// Finalize: losses[b,k] = xnorm[b] - 2*znorm[k,b] + hatnorm[k,b];
// argmin -> one-hot c; EMA of usage; obj = mean of assigned losses.
// Single block so no global atomics / zero-init needed.
// ---------------------------------------------------------------------------
__global__ __launch_bounds__(1024) void k_finalize(const float* __restrict__ znorm,
                                                   const float* __restrict__ hatnorm,
                                                   const float* __restrict__ xnorm,
                                                   const float* __restrict__ c_mean,
                                                   float* __restrict__ c,
                                                   float* __restrict__ c_mean_new,
                                                   float* __restrict__ obj) {
    __shared__ float cnt[Kk];
    __shared__ float objacc;
    int t = threadIdx.x;
    if (t < Kk) cnt[t] = 0.f;
    if (t == 0) objacc = 0.f;
    __syncthreads();

    float lobj = 0.f;
    for (int b = t; b < Bb; b += 1024) {
        float xn   = xnorm[b];
        float best = 3.4e38f;
        int   bi   = 0;
#pragma unroll
        for (int k = 0; k < Kk; ++k) {
            float l = xn - 2.f * znorm[k * Bb + b] + hatnorm[k * Bb + b];
            if (l < best) { best = l; bi = k; }   // strict < == first argmin
        }
#pragma unroll
        for (int k = 0; k < Kk; ++k)
            c[(size_t)b * Kk + k] = (k == bi) ? 1.f : 0.f;
        atomicAdd(&cnt[bi], 1.f);
        lobj += best;
    }

#pragma unroll
    for (int off = 32; off > 0; off >>= 1) lobj += __shfl_down(lobj, off, 64);
    if ((t & 63) == 0) atomicAdd(&objacc, lobj);
    __syncthreads();

    if (t < Kk) c_mean_new[t] = 0.9f * c_mean[t] + 0.1f * (cnt[t] * (1.f / Bb));
    if (t == 0) obj[0] = objacc * (1.f / Bb);
}

// ---------------------------------------------------------------------------
extern "C" void kernel_launch(void* const* d_in, const int* in_sizes, int n_in,
                              void* d_out, int out_size, void* d_ws, size_t ws_size,
                              hipStream_t stream) {
    const float* x      = (const float*)d_in[0];
    const float* Us     = (const float*)d_in[1];
    const float* c_mean = (const float*)d_in[2];

    float* out        = (float*)d_out;
    float* xhat       = out;                              // K*B*D
    float* c          = out + (size_t)Kk * Bb * Dd;       // B*K
    float* c_mean_new = c + (size_t)Bb * Kk;              // K
    float* obj        = c_mean_new + Kk;                  // 1

    float* ws      = (float*)d_ws;                        // needs ~8.7 MB
    float* z       = ws;                                  // K*B*d
    float* znorm   = z + (size_t)Kk * Bb * dd_;           // K*B
    float* hatnorm = znorm + (size_t)Kk * Bb;             // K*B
    float* xnorm   = hatnorm + (size_t)Kk * Bb;           // B

    k_xnorm   <<<Bb / 4,        256, 0, stream>>>(x, xnorm);
    k_encode  <<<Kk * (Bb / 64), 256, 0, stream>>>(x, Us, z, znorm);
    k_decode  <<<Kk * (Bb / 64), 256, 0, stream>>>(Us, z, xhat, hatnorm);
    k_finalize<<<1,             1024, 0, stream>>>(znorm, hatnorm, xnorm, c_mean,
                                                   c, c_mean_new, obj);
}

// Round 2
// 273.863 us; speedup vs baseline: 1.4202x; 1.4202x over previous
//
#include <hip/hip_runtime.h>

#define Kk  16
#define Bb  2048
#define Dd  1024
#define dd_ 64
#define BT  64      // b-rows per block
#define CH  64      // D-chunk (encode inner / decode output chunk)
#define PAD 68      // padded LDS row length (floats), 16B-aligned, 68%32=4

// ---------------------------------------------------------------------------
// xnorm[b] = ||x[b,:]||^2. One wave per row, full-BW grid.
// ---------------------------------------------------------------------------
__global__ __launch_bounds__(256) void k_xnorm(const float* __restrict__ x,
                                               float* __restrict__ xnorm) {
    int lane = threadIdx.x & 63;
    int w    = threadIdx.x >> 6;
    int b    = blockIdx.x * 4 + w;
    const float* xr = x + (size_t)b * Dd;
    float s = 0.f;
#pragma unroll
    for (int seg = 0; seg < 4; ++seg) {
        float4 v = *reinterpret_cast<const float4*>(xr + seg * 256 + lane * 4);
        s = fmaf(v.x, v.x, s); s = fmaf(v.y, v.y, s);
        s = fmaf(v.z, v.z, s); s = fmaf(v.w, v.w, s);
    }
#pragma unroll
    for (int off = 32; off > 0; off >>= 1) s += __shfl_down(s, off, 64);
    if (lane == 0) xnorm[b] = s;
}

// ---------------------------------------------------------------------------
// Fused encode+decode for one (k, 64-row b-tile):
//   z = x_tile @ Us[k]        (64x64, kept in LDS, + znorm)
//   x_ = z @ Us[k]^T          (64x1024, streamed out, + hatnorm in-block)
// 256 threads, 4x4 register tile each. a-frag: 16 distinct b128/wave (2-way,
// free); b-frag: 4 distinct (16-lane broadcast, free). VALU-bound by design.
// ---------------------------------------------------------------------------
__global__ __launch_bounds__(256) void k_fused(const float* __restrict__ x,
                                               const float* __restrict__ Us,
                                               float* __restrict__ xhat,
                                               float* __restrict__ znorm,
                                               float* __restrict__ hatnorm) {
    __shared__ float buf0[CH][PAD];    // x chunk (transposed) / UsT chunk
    __shared__ float buf1[CH][PAD];    // Us chunk (straight)
    __shared__ float z_lds[dd_][PAD];  // z transposed: [dcol][b]
    __shared__ float hat_lds[BT];

    int t  = threadIdx.x;
    int tx = t & 15;          // 16 distinct per wave
    int ty = t >> 4;          // 4 distinct per wave (broadcast dim)

    // XCD-aware bijective swizzle: 512 blocks, 64 per XCD chunk
    int bid = blockIdx.x;
    int sw  = (bid & 7) * 64 + (bid >> 3);
    int k   = sw >> 5;
    int b0  = (sw & 31) * BT;

    const float* __restrict__ xk  = x  + (size_t)b0 * Dd;
    const float* __restrict__ Usk = Us + (size_t)k * Dd * dd_;

    if (t < BT) hat_lds[t] = 0.f;

    // ---------------- encode: z[b][dcol] = sum_D x[b][D] Us[D][dcol] -------
    float acc[4][4];
#pragma unroll
    for (int i = 0; i < 4; ++i)
#pragma unroll
        for (int j = 0; j < 4; ++j) acc[i][j] = 0.f;

    for (int Dc = 0; Dc < Dd; Dc += CH) {
        __syncthreads();
#pragma unroll
        for (int rr = 0; rr < 4; ++rr) {
            int row = rr * 16 + ty;
            // x[b0+row][Dc + tx*4 .. +3]  -> buf0[kk][b] (transposed)
            float4 v = *reinterpret_cast<const float4*>(
                xk + (size_t)row * Dd + Dc + tx * 4);
            buf0[tx * 4 + 0][row] = v.x;
            buf0[tx * 4 + 1][row] = v.y;
            buf0[tx * 4 + 2][row] = v.z;
            buf0[tx * 4 + 3][row] = v.w;
            // Us[Dc+row][tx*4 .. +3] -> buf1[kk][dcol] (straight, b128 write)
            float4 u = *reinterpret_cast<const float4*>(
                Usk + (size_t)(Dc + row) * dd_ + tx * 4);
            *reinterpret_cast<float4*>(&buf1[row][tx * 4]) = u;
        }
        __syncthreads();
#pragma unroll 8
        for (int kk = 0; kk < CH; ++kk) {
            float4 av = *reinterpret_cast<const float4*>(&buf0[kk][tx * 4]);
            float4 bv = *reinterpret_cast<const float4*>(&buf1[kk][ty * 4]);
            float a_[4] = {av.x, av.y, av.z, av.w};
            float b_[4] = {bv.x, bv.y, bv.z, bv.w};
#pragma unroll
            for (int i = 0; i < 4; ++i)
#pragma unroll
                for (int j = 0; j < 4; ++j)
                    acc[i][j] = fmaf(a_[i], b_[j], acc[i][j]);
        }
    }

    // write z tile into LDS transposed: z_lds[dcol][b]
#pragma unroll
    for (int i = 0; i < 4; ++i)
#pragma unroll
        for (int j = 0; j < 4; ++j)
            z_lds[ty * 4 + j][tx * 4 + i] = acc[i][j];
    __syncthreads();

    // znorm[k][b] = ||z_b||^2
    if (t < BT) {
        float s = 0.f;
#pragma unroll 8
        for (int dc = 0; dc < dd_; ++dc) {
            float zv = z_lds[dc][t];
            s = fmaf(zv, zv, s);
        }
        znorm[k * Bb + b0 + t] = s;
    }

    // ---------------- decode: x_[b][D] = sum_dcol z[b][dcol] Us[D][dcol] ---
    float hat[4] = {0.f, 0.f, 0.f, 0.f};
    for (int Dc = 0; Dc < Dd; Dc += CH) {
        __syncthreads();
#pragma unroll
        for (int rr = 0; rr < 4; ++rr) {
            int row = rr * 16 + ty;
            // Us[Dc+row][tx*4 .. +3] -> buf0[dcol][D_local] (transposed)
            float4 u = *reinterpret_cast<const float4*>(
                Usk + (size_t)(Dc + row) * dd_ + tx * 4);
            buf0[tx * 4 + 0][row] = u.x;
            buf0[tx * 4 + 1][row] = u.y;
            buf0[tx * 4 + 2][row] = u.z;
            buf0[tx * 4 + 3][row] = u.w;
        }
        __syncthreads();

        float dacc[4][4];
#pragma unroll
        for (int i = 0; i < 4; ++i)
#pragma unroll
            for (int j = 0; j < 4; ++j) dacc[i][j] = 0.f;

#pragma unroll 8
        for (int kk = 0; kk < dd_; ++kk) {
            float4 av = *reinterpret_cast<const float4*>(&z_lds[kk][ty * 4]);
            float4 bv = *reinterpret_cast<const float4*>(&buf0[kk][tx * 4]);
            float a_[4] = {av.x, av.y, av.z, av.w};
            float b_[4] = {bv.x, bv.y, bv.z, bv.w};
#pragma unroll
            for (int i = 0; i < 4; ++i)
#pragma unroll
                for (int j = 0; j < 4; ++j)
                    dacc[i][j] = fmaf(a_[i], b_[j], dacc[i][j]);
        }

        // coalesced float4 stores: lanes tx cover 256B contiguous
#pragma unroll
        for (int i = 0; i < 4; ++i) {
            float4 o = make_float4(dacc[i][0], dacc[i][1], dacc[i][2], dacc[i][3]);
            *reinterpret_cast<float4*>(
                xhat + ((size_t)(k * Bb + b0 + ty * 4 + i)) * Dd + Dc + tx * 4) = o;
            hat[i] = fmaf(o.x, o.x, hat[i]);
            hat[i] = fmaf(o.y, o.y, hat[i]);
            hat[i] = fmaf(o.z, o.z, hat[i]);
            hat[i] = fmaf(o.w, o.w, hat[i]);
        }
    }

    __syncthreads();
#pragma unroll
    for (int i = 0; i < 4; ++i) atomicAdd(&hat_lds[ty * 4 + i], hat[i]);
    __syncthreads();
    if (t < BT) hatnorm[k * Bb + b0 + t] = hat_lds[t];
}

// ---------------------------------------------------------------------------
// Assign: losses -> argmin -> one-hot c; partial cnt/obj via global atomics.
// ---------------------------------------------------------------------------
__global__ __launch_bounds__(128) void k_assign(const float* __restrict__ znorm,
                                                const float* __restrict__ hatnorm,
                                                const float* __restrict__ xnorm,
                                                float* __restrict__ c,
                                                float* __restrict__ cnt_g,
                                                float* __restrict__ obj_g) {
    __shared__ float cnt[Kk];
    __shared__ float objacc;
    int t = threadIdx.x;
    int b = blockIdx.x * 128 + t;
    if (t < Kk) cnt[t] = 0.f;
    if (t == 0) objacc = 0.f;
    __syncthreads();

    float xn   = xnorm[b];
    float best = 3.4e38f;
    int   bi   = 0;
#pragma unroll
    for (int k = 0; k < Kk; ++k) {
        float l = xn - 2.f * znorm[k * Bb + b] + hatnorm[k * Bb + b];
        if (l < best) { best = l; bi = k; }   // strict <  == first argmin
    }
#pragma unroll
    for (int j = 0; j < 4; ++j) {
        float4 o;
        o.x = (bi == j * 4 + 0) ? 1.f : 0.f;
        o.y = (bi == j * 4 + 1) ? 1.f : 0.f;
        o.z = (bi == j * 4 + 2) ? 1.f : 0.f;
        o.w = (bi == j * 4 + 3) ? 1.f : 0.f;
        *reinterpret_cast<float4*>(&c[(size_t)b * Kk + j * 4]) = o;
    }
    atomicAdd(&cnt[bi], 1.f);

    float lobj = best;
#pragma unroll
    for (int off = 32; off > 0; off >>= 1) lobj += __shfl_down(lobj, off, 64);
    if ((t & 63) == 0) atomicAdd(&objacc, lobj);
    __syncthreads();

    if (t < Kk) atomicAdd(&cnt_g[t], cnt[t]);
    if (t == 0) atomicAdd(obj_g, objacc);
}

// ---------------------------------------------------------------------------
__global__ __launch_bounds__(64) void k_epilogue(const float* __restrict__ cnt_g,
                                                 const float* __restrict__ obj_g,
                                                 const float* __restrict__ c_mean,
                                                 float* __restrict__ c_mean_new,
                                                 float* __restrict__ obj) {
    int t = threadIdx.x;
    if (t < Kk) c_mean_new[t] = 0.9f * c_mean[t] + 0.1f * (cnt_g[t] * (1.f / Bb));
    if (t == 0) obj[0] = obj_g[0] * (1.f / Bb);
}

// ---------------------------------------------------------------------------
extern "C" void kernel_launch(void* const* d_in, const int* in_sizes, int n_in,
                              void* d_out, int out_size, void* d_ws, size_t ws_size,
                              hipStream_t stream) {
    const float* x      = (const float*)d_in[0];
    const float* Us     = (const float*)d_in[1];
    const float* c_mean = (const float*)d_in[2];

    float* out        = (float*)d_out;
    float* xhat       = out;                              // K*B*D
    float* c          = out + (size_t)Kk * Bb * Dd;       // B*K
    float* c_mean_new = c + (size_t)Bb * Kk;              // K
    float* obj        = c_mean_new + Kk;                  // 1

    float* ws      = (float*)d_ws;
    float* znorm   = ws;                                  // K*B
    float* hatnorm = znorm + (size_t)Kk * Bb;             // K*B
    float* xnorm   = hatnorm + (size_t)Kk * Bb;           // B
    float* cnt_g   = xnorm + Bb;                          // K
    float* obj_g   = cnt_g + Kk;                          // 1

    hipMemsetAsync(cnt_g, 0, (Kk + 1) * sizeof(float), stream);

    k_xnorm   <<<Bb / 4, 256, 0, stream>>>(x, xnorm);
    k_fused   <<<Kk * (Bb / BT), 256, 0, stream>>>(x, Us, xhat, znorm, hatnorm);
    k_assign  <<<Bb / 128, 128, 0, stream>>>(znorm, hatnorm, xnorm, c, cnt_g, obj_g);
    k_epilogue<<<1, 64, 0, stream>>>(cnt_g, obj_g, c_mean, c_mean_new, obj);
}